// Round 1
// baseline (3756.030 us; speedup 1.0000x reference)
//
#include <hip/hip_runtime.h>
#include <stdint.h>

#define BATCH_N   131072
#define HID       256
#define SPIKE_DIM 128
#define COORD_DIM 64
#define IN_DIM    192
#define STEPS     25
#define TILE      64
#define BLOCK     512
#define KCHUNK    24

// ws layout (floats)
#define W0T_OFF 0                        // [IN_DIM][HID]     49152
#define W1T_OFF (IN_DIM*HID)             // [HID][HID]        65536
#define WOT_OFF (W1T_OFF + HID*HID)      // [HID][COORD_DIM]  16384

__global__ __launch_bounds__(256)
void prep_kernel(const float* __restrict__ W0,
                 const float* __restrict__ W1,
                 const float* __restrict__ Wout,
                 float* __restrict__ ws) {
  int idx = blockIdx.x * 256 + threadIdx.x;
  if (idx < IN_DIM*HID) {               // W0T[j][i] = W0[i][j]
    int j = idx >> 8, i = idx & 255;
    ws[W0T_OFF + idx] = W0[i*IN_DIM + j];
  }
  int i1 = idx - IN_DIM*HID;            // W1T[j][i] = W1[i][j]
  if (i1 >= 0 && i1 < HID*HID) {
    int j = i1 >> 8, i = i1 & 255;
    ws[W1T_OFF + i1] = W1[i*HID + j];
  }
  int i2 = idx - (IN_DIM*HID + HID*HID);// WoT[k][c] = Wout[128+c][k]
  if (i2 >= 0 && i2 < HID*COORD_DIM) {
    int k = i2 >> 6, c = i2 & 63;
    ws[WOT_OFF + i2] = Wout[(SPIKE_DIM + c)*HID + k];
  }
}

__global__ __launch_bounds__(BLOCK)
void snn_kernel(const float* __restrict__ spk,
                const float* __restrict__ crd,
                const float* __restrict__ b0,
                const float* __restrict__ b1,
                const float* __restrict__ bout,
                const float* __restrict__ ws,
                float* __restrict__ out) {
  __shared__ float xs[TILE*IN_DIM];     // 12288 floats = 48 KB
  __shared__ float wch[KCHUNK*HID];     //  6144 floats = 24 KB  (72 KB total -> 2 blocks/CU)

  const int tid  = threadIdx.x;
  const int lane = tid & 63;
  const int wv   = tid >> 6;            // wave 0..7
  const int e0   = blockIdx.x * TILE;
  const int i4   = lane * 4;            // this lane's 4 output neurons: i4..i4+3
  const int eb   = wv * 8;              // this wave's 8 elements (local)

  // ---- stage x tile (spikes || coords) into LDS, coalesced float4 ----
  {
    const float4* sp4 = (const float4*)(spk + (size_t)e0 * SPIKE_DIM);
    for (int t = tid; t < TILE*SPIKE_DIM/4; t += BLOCK) {
      int e = t >> 5, j = (t & 31) * 4;          // 32 float4 per spike row
      *(float4*)&xs[e*IN_DIM + j] = sp4[t];
    }
    const float4* cr4 = (const float4*)(crd + (size_t)e0 * COORD_DIM);
    for (int t = tid; t < TILE*COORD_DIM/4; t += BLOCK) {
      int e = t >> 4, j = (t & 15) * 4;          // 16 float4 per coord row
      *(float4*)&xs[e*IN_DIM + SPIKE_DIM + j] = cr4[t];
    }
  }

  // ---- Phase A: c0 = x @ W0^T  (thread owns 8 elems x 4 outputs) ----
  float acc[8][4];
  #pragma unroll
  for (int ee = 0; ee < 8; ++ee)
    acc[ee][0] = acc[ee][1] = acc[ee][2] = acc[ee][3] = 0.0f;

  const float* W0T = ws + W0T_OFF;
  for (int kc = 0; kc < IN_DIM/KCHUNK; ++kc) {
    __syncthreads();
    const float4* src = (const float4*)(W0T + kc*KCHUNK*HID);
    for (int t = tid; t < KCHUNK*HID/4; t += BLOCK)
      *(float4*)&wch[t*4] = src[t];
    __syncthreads();
    for (int j = 0; j < KCHUNK; ++j) {
      float4 w = *(const float4*)&wch[j*HID + i4];
      int jj = kc*KCHUNK + j;
      #pragma unroll
      for (int ee = 0; ee < 8; ++ee) {
        float xv = xs[(eb+ee)*IN_DIM + jj];      // wave-uniform addr -> LDS broadcast
        acc[ee][0] += xv * w.x;
        acc[ee][1] += xv * w.y;
        acc[ee][2] += xv * w.z;
        acc[ee][3] += xv * w.w;
      }
    }
  }

  // ---- Phase B: 25-step LIF recurrence, one wave per element ----
  const float* W1T = ws + W1T_OFF;
  const float* WoT = ws + WOT_OFF;
  float4 b0v = *(const float4*)&b0[i4];
  float4 b1v = *(const float4*)&b1[i4];
  float  bc  = bout[SPIKE_DIM + lane];

  for (int ee = 0; ee < 8; ++ee) {
    const int e = e0 + eb + ee;
    const float c0x = acc[ee][0] + b0v.x;
    const float c0y = acc[ee][1] + b0v.y;
    const float c0z = acc[ee][2] + b0v.z;
    const float c0w = acc[ee][3] + b0v.w;

    float v0x=0.f, v0y=0.f, v0z=0.f, v0w=0.f;
    float v1x=0.f, v1y=0.f, v1z=0.f, v1w=0.f;
    float s1x=0.f, s1y=0.f, s1z=0.f, s1w=0.f;

    for (int t = 0; t < STEPS; ++t) {
      // LIF layer 0 — numpy rounding order (no FMA contraction)
      bool sp;
      unsigned long long m0, m1, m2, m3;
      v0x = __fmul_rn(0.7f, v0x) + __fmul_rn(0.3f, c0x);
      sp = (v0x >= 1.0f); m0 = __ballot(sp); if (sp) v0x = 0.f;
      v0y = __fmul_rn(0.7f, v0y) + __fmul_rn(0.3f, c0y);
      sp = (v0y >= 1.0f); m1 = __ballot(sp); if (sp) v0y = 0.f;
      v0z = __fmul_rn(0.7f, v0z) + __fmul_rn(0.3f, c0z);
      sp = (v0z >= 1.0f); m2 = __ballot(sp); if (sp) v0z = 0.f;
      v0w = __fmul_rn(0.7f, v0w) + __fmul_rn(0.3f, c0w);
      sp = (v0w >= 1.0f); m3 = __ballot(sp); if (sp) v0w = 0.f;

      // c1 = b1 + sum of active W1 columns (sparse gather, depth-2 pipelined)
      float c1x = b1v.x, c1y = b1v.y, c1z = b1v.z, c1w = b1v.w;
      float4 wcur = make_float4(0.f, 0.f, 0.f, 0.f);
      int have = 0;
      unsigned long long mm;
      #define PROCQ(MASK, Q)                                                    \
        mm = (MASK);                                                            \
        while (mm) {                                                            \
          int l = __builtin_ctzll(mm); mm &= mm - 1;                            \
          float4 wn = *(const float4*)&W1T[(l*4 + (Q))*HID + i4];               \
          if (have) { c1x += wcur.x; c1y += wcur.y; c1z += wcur.z; c1w += wcur.w; } \
          wcur = wn; have = 1;                                                  \
        }
      PROCQ(m0, 0)
      PROCQ(m1, 1)
      PROCQ(m2, 2)
      PROCQ(m3, 3)
      #undef PROCQ
      if (have) { c1x += wcur.x; c1y += wcur.y; c1z += wcur.z; c1w += wcur.w; }

      // LIF layer 1
      v1x = __fmul_rn(0.7f, v1x) + __fmul_rn(0.3f, c1x);
      sp = (v1x >= 1.0f); s1x = sp ? 1.f : 0.f; if (sp) v1x = 0.f;
      v1y = __fmul_rn(0.7f, v1y) + __fmul_rn(0.3f, c1y);
      sp = (v1y >= 1.0f); s1y = sp ? 1.f : 0.f; if (sp) v1y = 0.f;
      v1z = __fmul_rn(0.7f, v1z) + __fmul_rn(0.3f, c1z);
      sp = (v1z >= 1.0f); s1z = sp ? 1.f : 0.f; if (sp) v1z = 0.f;
      v1w = __fmul_rn(0.7f, v1w) + __fmul_rn(0.3f, c1w);
      sp = (v1w >= 1.0f); s1w = sp ? 1.f : 0.f; if (sp) v1w = 0.f;
    }

    // next_action = sign(s1) = s1 (values are 0/1)
    *(float4*)&out[(size_t)e*HID + i4] = make_float4(s1x, s1y, s1z, s1w);

    // next_coords = b_out[128:] + sum of active W_out coord columns
    unsigned long long f0 = __ballot(s1x > 0.5f);
    unsigned long long f1 = __ballot(s1y > 0.5f);
    unsigned long long f2 = __ballot(s1z > 0.5f);
    unsigned long long f3 = __ballot(s1w > 0.5f);
    float cacc = bc;
    unsigned long long mm;
    #define CPROCQ(MASK, Q)                                   \
      mm = (MASK);                                            \
      while (mm) {                                            \
        int l = __builtin_ctzll(mm); mm &= mm - 1;            \
        cacc += WoT[(l*4 + (Q))*COORD_DIM + lane];            \
      }
    CPROCQ(f0, 0)
    CPROCQ(f1, 1)
    CPROCQ(f2, 2)
    CPROCQ(f3, 3)
    #undef CPROCQ
    out[(size_t)BATCH_N*HID + (size_t)e*COORD_DIM + lane] = cacc;
  }
}

extern "C" void kernel_launch(void* const* d_in, const int* in_sizes, int n_in,
                              void* d_out, int out_size, void* d_ws, size_t ws_size,
                              hipStream_t stream) {
  (void)in_sizes; (void)n_in; (void)out_size; (void)ws_size;
  const float* spk = (const float*)d_in[0];
  const float* crd = (const float*)d_in[1];
  const float* W0  = (const float*)d_in[2];
  const float* b0  = (const float*)d_in[3];
  const float* W1  = (const float*)d_in[4];
  const float* b1  = (const float*)d_in[5];
  const float* Wo  = (const float*)d_in[6];
  const float* bo  = (const float*)d_in[7];
  float* ws  = (float*)d_ws;
  float* out = (float*)d_out;

  hipLaunchKernelGGL(prep_kernel, dim3(512), dim3(256), 0, stream, W0, W1, Wo, ws);
  hipLaunchKernelGGL(snn_kernel, dim3(BATCH_N/TILE), dim3(BLOCK), 0, stream,
                     spk, crd, b0, b1, bo, ws, out);
}

// Round 2
// 563.238 us; speedup vs baseline: 6.6686x; 6.6686x over previous
//
#include <hip/hip_runtime.h>
#include <stdint.h>

#define BATCH_N   131072
#define HID       256
#define SPIKE_DIM 128
#define COORD_DIM 64
#define IN_DIM    192
#define STEPS     25
#define TILE      32
#define BLOCK     512
#define KCHUNK    24

typedef float f4 __attribute__((ext_vector_type(4)));

// ws layout (floats)
#define W0T_OFF 0                        // [IN_DIM][HID]     49152
#define W1T_OFF (IN_DIM*HID)             // [HID][HID]        65536
#define WOT_OFF (W1T_OFF + HID*HID)      // [HID][COORD_DIM]  16384

__global__ __launch_bounds__(256)
void prep_kernel(const float* __restrict__ W0,
                 const float* __restrict__ W1,
                 const float* __restrict__ Wout,
                 float* __restrict__ ws) {
  int idx = blockIdx.x * 256 + threadIdx.x;
  if (idx < IN_DIM*HID) {               // W0T[j][i] = W0[i][j]
    int j = idx >> 8, i = idx & 255;
    ws[W0T_OFF + idx] = W0[i*IN_DIM + j];
  }
  int i1 = idx - IN_DIM*HID;            // W1T[j][i] = W1[i][j]
  if (i1 >= 0 && i1 < HID*HID) {
    int j = i1 >> 8, i = i1 & 255;
    ws[W1T_OFF + i1] = W1[i*HID + j];
  }
  int i2 = idx - (IN_DIM*HID + HID*HID);// WoT[k][c] = Wout[128+c][k]
  if (i2 >= 0 && i2 < HID*COORD_DIM) {
    int k = i2 >> 6, c = i2 & 63;
    ws[WOT_OFF + i2] = Wout[(SPIKE_DIM + c)*HID + k];
  }
}

__global__ __launch_bounds__(BLOCK)
void snn_kernel(const float* __restrict__ spk,
                const float* __restrict__ crd,
                const float* __restrict__ b0,
                const float* __restrict__ b1,
                const float* __restrict__ bout,
                const float* __restrict__ ws,
                float* __restrict__ out) {
  // 48 KB LDS total -> 3 blocks/CU.
  // Phase A view: xs[TILE][IN_DIM] (6144 f) + wch[KCHUNK][HID] (6144 f)
  // Phase B view: c0s[TILE][HID]   (8192 f) aliased on top (written after last
  //               use of xs/wch, behind __syncthreads()).
  __shared__ float smem[TILE*IN_DIM + KCHUNK*HID];
  float* xs  = smem;
  float* wch = smem + TILE*IN_DIM;
  float* c0s = smem;

  const int tid  = threadIdx.x;
  const int lane = tid & 63;
  const int wv   = tid >> 6;            // wave 0..7
  const int e0   = blockIdx.x * TILE;
  const int i4   = lane * 4;            // this lane's 4 neurons: i4..i4+3
  const int eb   = wv * 4;              // this wave's 4 elements (local)

  // ---- stage x tile (spikes || coords) into LDS, nontemporal f4 loads ----
  {
    const f4* sp4 = (const f4*)(spk + (size_t)e0 * SPIKE_DIM);
    for (int t = tid; t < TILE*SPIKE_DIM/4; t += BLOCK) {
      int e = t >> 5, j = (t & 31) * 4;          // 32 f4 per spike row
      *(f4*)&xs[e*IN_DIM + j] = __builtin_nontemporal_load(&sp4[t]);
    }
    const f4* cr4 = (const f4*)(crd + (size_t)e0 * COORD_DIM);
    for (int t = tid; t < TILE*COORD_DIM/4; t += BLOCK) {
      int e = t >> 4, j = (t & 15) * 4;          // 16 f4 per coord row
      *(f4*)&xs[e*IN_DIM + SPIKE_DIM + j] = __builtin_nontemporal_load(&cr4[t]);
    }
  }

  // ---- Phase A: c0 = x @ W0^T (thread: 4 elems x 4 outputs, regs only) ----
  float acc[4][4];
  #pragma unroll
  for (int ee = 0; ee < 4; ++ee)
    acc[ee][0] = acc[ee][1] = acc[ee][2] = acc[ee][3] = 0.0f;

  const float* W0T = ws + W0T_OFF;
  for (int kc = 0; kc < IN_DIM/KCHUNK; ++kc) {
    __syncthreads();
    const f4* src = (const f4*)(W0T + kc*KCHUNK*HID);
    for (int t = tid; t < KCHUNK*HID/4; t += BLOCK)
      *(f4*)&wch[t*4] = src[t];                  // L2-cached weight reads
    __syncthreads();
    for (int j = 0; j < KCHUNK; ++j) {
      f4 w = *(const f4*)&wch[j*HID + i4];
      int jj = kc*KCHUNK + j;
      #pragma unroll
      for (int ee = 0; ee < 4; ++ee) {
        float xv = xs[(eb+ee)*IN_DIM + jj];      // wave-uniform -> LDS broadcast
        acc[ee][0] += xv * w.x;
        acc[ee][1] += xv * w.y;
        acc[ee][2] += xv * w.z;
        acc[ee][3] += xv * w.w;
      }
    }
  }

  // ---- dump c0 (+bias) to LDS with compile-time indices (no scratch) ----
  f4 b0v = *(const f4*)&b0[i4];
  f4 b1v = *(const f4*)&b1[i4];
  float bc = bout[SPIKE_DIM + lane];
  __syncthreads();
  #pragma unroll
  for (int ee = 0; ee < 4; ++ee) {
    f4 c;
    c.x = acc[ee][0] + b0v.x;
    c.y = acc[ee][1] + b0v.y;
    c.z = acc[ee][2] + b0v.z;
    c.w = acc[ee][3] + b0v.w;
    *(f4*)&c0s[(eb+ee)*HID + i4] = c;
  }
  __syncthreads();

  // ---- Phase B: 25-step LIF recurrence, one wave per element ----
  const float* W1T = ws + W1T_OFF;
  const float* WoT = ws + WOT_OFF;

  for (int ee = 0; ee < 4; ++ee) {
    const int e = e0 + eb + ee;
    f4 c0q = *(const f4*)&c0s[(eb+ee)*HID + i4];
    const float c0x = c0q.x, c0y = c0q.y, c0z = c0q.z, c0w = c0q.w;

    float v0x=0.f, v0y=0.f, v0z=0.f, v0w=0.f;
    float v1x=0.f, v1y=0.f, v1z=0.f, v1w=0.f;
    float s1x=0.f, s1y=0.f, s1z=0.f, s1w=0.f;

    for (int t = 0; t < STEPS; ++t) {
      // LIF layer 0 — numpy rounding order (no FMA contraction)
      bool sp;
      unsigned long long m0, m1, m2, m3;
      v0x = __fmul_rn(0.7f, v0x) + __fmul_rn(0.3f, c0x);
      sp = (v0x >= 1.0f); m0 = __ballot(sp); if (sp) v0x = 0.f;
      v0y = __fmul_rn(0.7f, v0y) + __fmul_rn(0.3f, c0y);
      sp = (v0y >= 1.0f); m1 = __ballot(sp); if (sp) v0y = 0.f;
      v0z = __fmul_rn(0.7f, v0z) + __fmul_rn(0.3f, c0z);
      sp = (v0z >= 1.0f); m2 = __ballot(sp); if (sp) v0z = 0.f;
      v0w = __fmul_rn(0.7f, v0w) + __fmul_rn(0.3f, c0w);
      sp = (v0w >= 1.0f); m3 = __ballot(sp); if (sp) v0w = 0.f;

      // c1 = b1 + sum of active W1 columns (sparse gather, depth-2 pipelined)
      float c1x = b1v.x, c1y = b1v.y, c1z = b1v.z, c1w = b1v.w;
      f4 wcur; wcur.x = wcur.y = wcur.z = wcur.w = 0.f;
      int have = 0;
      unsigned long long mm;
      #define PROCQ(MASK, Q)                                                    \
        mm = (MASK);                                                            \
        while (mm) {                                                            \
          int l = __builtin_ctzll(mm); mm &= mm - 1;                            \
          f4 wn = *(const f4*)&W1T[(l*4 + (Q))*HID + i4];                       \
          if (have) { c1x += wcur.x; c1y += wcur.y; c1z += wcur.z; c1w += wcur.w; } \
          wcur = wn; have = 1;                                                  \
        }
      PROCQ(m0, 0)
      PROCQ(m1, 1)
      PROCQ(m2, 2)
      PROCQ(m3, 3)
      #undef PROCQ
      if (have) { c1x += wcur.x; c1y += wcur.y; c1z += wcur.z; c1w += wcur.w; }

      // LIF layer 1
      v1x = __fmul_rn(0.7f, v1x) + __fmul_rn(0.3f, c1x);
      sp = (v1x >= 1.0f); s1x = sp ? 1.f : 0.f; if (sp) v1x = 0.f;
      v1y = __fmul_rn(0.7f, v1y) + __fmul_rn(0.3f, c1y);
      sp = (v1y >= 1.0f); s1y = sp ? 1.f : 0.f; if (sp) v1y = 0.f;
      v1z = __fmul_rn(0.7f, v1z) + __fmul_rn(0.3f, c1z);
      sp = (v1z >= 1.0f); s1z = sp ? 1.f : 0.f; if (sp) v1z = 0.f;
      v1w = __fmul_rn(0.7f, v1w) + __fmul_rn(0.3f, c1w);
      sp = (v1w >= 1.0f); s1w = sp ? 1.f : 0.f; if (sp) v1w = 0.f;
    }

    // next_action = sign(s1) = s1 (values are 0/1); nontemporal store
    f4 res; res.x = s1x; res.y = s1y; res.z = s1z; res.w = s1w;
    __builtin_nontemporal_store(res, (f4*)&out[(size_t)e*HID + i4]);

    // next_coords = b_out[128:] + sum of active W_out coord columns
    unsigned long long f0 = __ballot(s1x > 0.5f);
    unsigned long long f1 = __ballot(s1y > 0.5f);
    unsigned long long f2 = __ballot(s1z > 0.5f);
    unsigned long long f3 = __ballot(s1w > 0.5f);
    float cacc = bc;
    unsigned long long mm;
    #define CPROCQ(MASK, Q)                                   \
      mm = (MASK);                                            \
      while (mm) {                                            \
        int l = __builtin_ctzll(mm); mm &= mm - 1;            \
        cacc += WoT[(l*4 + (Q))*COORD_DIM + lane];            \
      }
    CPROCQ(f0, 0)
    CPROCQ(f1, 1)
    CPROCQ(f2, 2)
    CPROCQ(f3, 3)
    #undef CPROCQ
    __builtin_nontemporal_store(cacc,
        &out[(size_t)BATCH_N*HID + (size_t)e*COORD_DIM + lane]);
  }
}

extern "C" void kernel_launch(void* const* d_in, const int* in_sizes, int n_in,
                              void* d_out, int out_size, void* d_ws, size_t ws_size,
                              hipStream_t stream) {
  (void)in_sizes; (void)n_in; (void)out_size; (void)ws_size;
  const float* spk = (const float*)d_in[0];
  const float* crd = (const float*)d_in[1];
  const float* W0  = (const float*)d_in[2];
  const float* b0  = (const float*)d_in[3];
  const float* W1  = (const float*)d_in[4];
  const float* b1  = (const float*)d_in[5];
  const float* Wo  = (const float*)d_in[6];
  const float* bo  = (const float*)d_in[7];
  float* ws  = (float*)d_ws;
  float* out = (float*)d_out;

  hipLaunchKernelGGL(prep_kernel, dim3(512), dim3(256), 0, stream, W0, W1, Wo, ws);
  hipLaunchKernelGGL(snn_kernel, dim3(BATCH_N/TILE), dim3(BLOCK), 0, stream,
                     spk, crd, b0, b1, bo, ws, out);
}